// Round 6
// baseline (287.516 us; speedup 1.0000x reference)
//
#include <hip/hip_runtime.h>
#include <math.h>

#define NB 8
#define NC 19
#define HH 768
#define WW 768
#define HWSZ (HH*WW)          // 589824
#define OHH 96
#define OWW 96
#define DSN (NB*OHH*OWW)      // 73728
#define MIN_KEPT_DS 1562
#define TOPKK 128
#define IGNV (-100)
#define SEGS 144              // 4096-px segments per sample

typedef float f32x4 __attribute__((ext_vector_type(4)));
typedef int   i32x4 __attribute__((ext_vector_type(4)));

// ---- workspace layout (bytes) ----
#define HIST1_OFF  0x00000ull      // 8*4096*4 = 131072
#define CTRL_OFF   0x20000ull
#define ZERO_BYTES 0x20400ull      // hist1 + ctrl
#define PREDDS_OFF 0x21000ull      // 73728*4 = 294912 -> ends 0x69000
#define LOSS_OFF   0x70000ull      // 8*589824*4 = 18874368 -> ends 0x1270000
#define CAND_OFF   0x1270000ull    // 8*32768*4 = 1 MB -> total 20.4 MB
#define CAND_CAP   32768u

struct Ctrl {
  float thr;
  unsigned cand_cnt[NB];
};

// ---- ascending wave select (lanes 0..63): first bin where prefix-count >= rank ----
__device__ __forceinline__ void wave_select_asc(const unsigned* h, int nbins, unsigned rank,
                                                unsigned* out_bin, unsigned* out_rem) {
  int lane = threadIdx.x;
  int ch = nbins >> 6;
  int base = lane * ch;
  unsigned c = 0;
  for (int i = 0; i < ch; ++i) c += h[base + i];
  unsigned s = c;
#pragma unroll
  for (int off = 1; off < 64; off <<= 1) {
    unsigned so = (unsigned)__shfl_up((int)s, off);
    if (lane >= off) s += so;
  }
  unsigned long long ball = __ballot(s >= rank);
  int chunk = (int)__ffsll((unsigned long long)ball) - 1;
  if (lane == chunk) {
    unsigned cum = s - c;
    int bin = base;
    for (int b = base; b < base + ch; ++b) {
      unsigned cc = h[b];
      if (cum + cc >= rank) { bin = b; break; }
      cum += cc;
    }
    *out_bin = (unsigned)bin;
    *out_rem = rank - cum;   // 1-indexed rank within bin
  }
}

// ---- descending wave select with sums (lanes 0..63 of wave 0) ----
__device__ __forceinline__ void wave_sel_desc_sh(const unsigned* h, const float* fs,
                                                 int nbins, unsigned rank,
                                                 unsigned* o_bin, unsigned* o_cnt,
                                                 float* o_sum, unsigned* o_rem) {
  int lane = threadIdx.x;
  int ch = nbins >> 6;
  int base = lane * ch;
  unsigned c = 0; float f = 0.0f;
  for (int i = 0; i < ch; ++i) { c += h[base + i]; f += fs[base + i]; }
  unsigned s = c; float g = f;
#pragma unroll
  for (int off = 1; off < 64; off <<= 1) {
    unsigned so = (unsigned)__shfl_down((int)s, off);
    float go = __shfl_down(g, off);
    if (lane + off < 64) { s += so; g += go; }
  }
  unsigned long long ball = __ballot(s >= rank);
  int chunk = 63 - (int)__clzll(ball | 1ull);
  if (lane == chunk) {
    unsigned cum = s - c;
    float sab = g - f;
    int bin = base;
    for (int b = base + ch - 1; b >= base; --b) {
      unsigned cc = h[b];
      if (cum + cc >= rank) { bin = b; break; }
      cum += cc; sab += fs[b];
    }
    *o_bin = (unsigned)bin;
    *o_cnt = cum;
    *o_sum = sab;
    *o_rem = rank - cum;
  }
}

// ---------- Kernel 1: downsampled true-class prob, row-coalesced (+ ws zero) ----------
__global__ __launch_bounds__(256) void ds_eval(const float* __restrict__ pred,
                                               const int* __restrict__ tgt,
                                               float* __restrict__ pred_ds,
                                               float4* __restrict__ wzero) {
  __shared__ __align__(16) float rowbuf[4][WW];
  __shared__ float vals[192][NC];
  __shared__ float pr[2][192];
  __shared__ int sh_tc[OWW];
  __shared__ unsigned sh_val[OWW];

  int oy = blockIdx.x;
  int n = blockIdx.y;
  int tid = threadIdx.x;
  const float SY = (float)(767.0 / 95.0);

  {
    int blk = n * 96 + oy;
    int nw = (int)(ZERO_BYTES / 16);
    if (tid < 45) {
      int i = blk * 45 + tid;
      if (i < nw) wzero[i] = make_float4(0.f, 0.f, 0.f, 0.f);
    }
  }

  float cy = (float)oy * SY;
  int y0 = (int)floorf(cy);
  int y1 = min(y0 + 1, HH - 1);
  float fy = cy - (float)y0;
  int iy = min((int)floorf(cy + 0.5f), HH - 1);

  if (tid < OWW) {
    float cx = (float)tid * SY;
    int ix = min((int)floorf(cx + 0.5f), WW - 1);
    int t = tgt[(size_t)n * HWSZ + (size_t)iy * WW + ix];
    sh_val[tid] = (t != IGNV);
    sh_tc[tid] = t < 0 ? 0 : (t > (NC - 1) ? (NC - 1) : t);
  }
  __syncthreads();

  const float* base = pred + (size_t)n * NC * HWSZ;
  int rows[2] = { y0, y1 };
#pragma unroll
  for (int r = 0; r < 2; ++r) {
    const float* rbase = base + (size_t)rows[r] * WW;
    for (int c0 = 0; c0 < NC; c0 += 4) {
      int ncc = (NC - c0) < 4 ? (NC - c0) : 4;
      for (int k = tid; k < ncc * 192; k += 256) {
        int cc = k / 192, q = k % 192;
        ((float4*)rowbuf[cc])[q] = ((const float4*)(rbase + (size_t)(c0 + cc) * HWSZ))[q];
      }
      __syncthreads();
      if (tid < 192) {
        int col = min((int)floorf((float)(tid >> 1) * SY) + (tid & 1), WW - 1);
        for (int cc = 0; cc < ncc; ++cc) vals[tid][c0 + cc] = rowbuf[cc][col];
      }
      __syncthreads();
    }
    if (tid < 192) {
      int tc = sh_tc[tid >> 1];
      float m = -INFINITY, lt = 0.0f;
#pragma unroll
      for (int c = 0; c < NC; ++c) m = fmaxf(m, vals[tid][c]);
      float s = 0.0f;
#pragma unroll
      for (int c = 0; c < NC; ++c) {
        float v = vals[tid][c];
        s += expf(v - m);
        lt = (c == tc) ? v : lt;
      }
      pr[r][tid] = expf(lt - m) / s;
    }
    __syncthreads();
  }

  if (tid < OWW) {
    int ox = tid;
    float cx = (float)ox * SY;
    int x0 = (int)floorf(cx);
    float fx = cx - (float)x0;
    float py0 = pr[0][2 * ox] * (1.0f - fy) + pr[1][2 * ox] * fy;
    float py1 = pr[0][2 * ox + 1] * (1.0f - fy) + pr[1][2 * ox + 1] * fy;
    float out = py0 * (1.0f - fx) + py1 * fx;
    pred_ds[(size_t)n * (OHH * OWW) + oy * OWW + ox] = sh_val[ox] ? out : INFINITY;
  }
}

// ---------- Kernel 2: exact kth-smallest of pred_ds -> threshold ----------
__global__ __launch_bounds__(1024) void select_ds(const float* __restrict__ pred_ds,
                                                  Ctrl* ctrl) {
  __shared__ unsigned h[4096];
  __shared__ unsigned sb, srem;
  int tid = threadIdx.x;

  for (int i = tid; i < 4096; i += 1024) h[i] = 0;
  __syncthreads();
  for (int i = tid; i < DSN; i += 1024) {
    unsigned u = __float_as_uint(pred_ds[i]);
    atomicAdd(&h[u >> 20], 1u);
  }
  __syncthreads();
  unsigned nv = DSN - h[0x7F8];
  unsigned kq = nv < (unsigned)MIN_KEPT_DS ? nv : (unsigned)MIN_KEPT_DS;
  unsigned rank = kq > 0 ? kq : 1;
  if (tid < 64) wave_select_asc(h, 4096, rank, &sb, &srem);
  __syncthreads();
  unsigned b1 = sb, rem1 = srem;

  for (int i = tid; i < 4096; i += 1024) h[i] = 0;
  __syncthreads();
  for (int i = tid; i < DSN; i += 1024) {
    unsigned u = __float_as_uint(pred_ds[i]);
    if ((u >> 20) == b1) atomicAdd(&h[(u >> 8) & 0xFFFu], 1u);
  }
  __syncthreads();
  if (tid < 64) wave_select_asc(h, 4096, rem1, &sb, &srem);
  __syncthreads();
  unsigned b2 = sb, rem2 = srem;
  unsigned pfx = (b1 << 12) | b2;

  for (int i = tid; i < 256; i += 1024) h[i] = 0;
  __syncthreads();
  for (int i = tid; i < DSN; i += 1024) {
    unsigned u = __float_as_uint(pred_ds[i]);
    if ((u >> 8) == pfx) atomicAdd(&h[u & 0xFFu], 1u);
  }
  __syncthreads();
  if (tid < 64) wave_select_asc(h, 256, rem2, &sb, &srem);
  __syncthreads();

  if (tid == 0) {
    float kthv = __uint_as_float((pfx << 8) | sb);
    float thr = (kthv > 0.7f) ? kthv : 0.7f;
    if ((unsigned)MIN_KEPT_DS >= nv) thr = 1.0f;
    ctrl->thr = thr;
  }
}

// ---------- Kernel 3: main pass — softmax+NLL -> loss map + fused coarse hist ----------
__global__ __launch_bounds__(256) void main_pass(const float* __restrict__ pred,
                                                 const int* __restrict__ tgt,
                                                 const float* __restrict__ wgt,
                                                 const Ctrl* __restrict__ ctrl,
                                                 float* __restrict__ loss_full,
                                                 unsigned* __restrict__ hist1) {
  __shared__ unsigned h[4096];
  for (int i = threadIdx.x; i < 4096; i += 256) h[i] = 0;
  __syncthreads();

  int blk = blockIdx.x;          // 0..NB*SEGS-1
  int n = blk / SEGS;
  int seg = blk % SEGS;
  const float thr = ctrl->thr;
  const float* basep = pred + (size_t)n * NC * HWSZ;
  const int* tgtb = tgt + (size_t)n * HWSZ;
  float* lossb = loss_full + (size_t)n * HWSZ;

  for (int chunk = 0; chunk < 4; ++chunk) {
    int hw = seg * 4096 + chunk * 1024 + threadIdx.x * 4;

    const f32x4* pb = (const f32x4*)(basep + hw);
    f32x4 v[NC];
#pragma unroll
    for (int c = 0; c < NC; ++c)
      v[c] = __builtin_nontemporal_load(&pb[(size_t)c * (HWSZ / 4)]);

    i32x4 t4 = *(const i32x4*)(tgtb + hw);
    int tc[4]; bool val[4]; float m[4], s[4], lt[4];
#pragma unroll
    for (int j = 0; j < 4; ++j) {
      int tv = t4[j];
      val[j] = (tv != IGNV);
      int tcl = tv < 0 ? 0 : (tv > (NC - 1) ? (NC - 1) : tv);
      tc[j] = tcl;
      m[j] = -INFINITY; s[j] = 0.0f; lt[j] = 0.0f;
    }
#pragma unroll
    for (int c = 0; c < NC; ++c) {
#pragma unroll
      for (int j = 0; j < 4; ++j) m[j] = fmaxf(m[j], v[c][j]);
    }
#pragma unroll
    for (int c = 0; c < NC; ++c) {
#pragma unroll
      for (int j = 0; j < 4; ++j) {
        float x = v[c][j];
        s[j] += __expf(x - m[j]);
        lt[j] = (c == tc[j]) ? x : lt[j];
      }
    }

    f32x4 lo;
#pragma unroll
    for (int j = 0; j < 4; ++j) {
      float d = lt[j] - m[j];
      float p = __expf(d) / s[j];
      float logp = d - __logf(s[j]);
      float nll = -logp * wgt[tc[j]];
      float loss = (val[j] && p <= thr) ? nll : 0.0f;
      loss = fmaxf(loss, 0.0f);      // canonicalize -0/neg-ulp -> +0
      lo[j] = loss;
      unsigned u = __float_as_uint(loss);
      if (u) atomicAdd(&h[u >> 20], 1u);
    }
    *(f32x4*)(lossb + hw) = lo;
  }

  __syncthreads();
  for (int i = threadIdx.x; i < 4096; i += 256) {
    unsigned c = h[i];
    if (c) atomicAdd(&hist1[(size_t)n * 4096 + i], c);
  }
}

// ---------- Kernel 4: collect candidates (all losses >= coarse-bin floor) ----------
__global__ __launch_bounds__(256) void collect(const f32x4* __restrict__ loss4,
                                               const unsigned* __restrict__ hist1,
                                               Ctrl* __restrict__ ctrl,
                                               float* __restrict__ cand) {
  __shared__ unsigned sh_b1;
  int n = blockIdx.y;
  int tid = threadIdx.x;

  if (tid < 64) {
    const unsigned* hh = hist1 + (size_t)n * 4096;
    int lane = tid;
    int base = lane * 64;
    unsigned c = 0;
    for (int i = 0; i < 64; ++i) c += hh[base + i];
    unsigned s = c;
#pragma unroll
    for (int off = 1; off < 64; off <<= 1) {
      unsigned so = (unsigned)__shfl_down((int)s, off);
      if (lane + off < 64) s += so;
    }
    unsigned long long ball = __ballot(s >= (unsigned)TOPKK);
    if (ball == 0ull) {
      if (lane == 0) sh_b1 = 0u;       // <128 positives: collect all nonzero
    } else {
      int chunk = 63 - (int)__clzll(ball);
      if (lane == chunk) {
        unsigned cum = s - c;
        int bin = base;
        for (int b = base + 63; b >= base; --b) {
          unsigned cc = hh[b];
          if (cum + cc >= (unsigned)TOPKK) { bin = b; break; }
          cum += cc;
        }
        sh_b1 = (unsigned)bin;
      }
    }
  }
  __syncthreads();
  unsigned thr_u = sh_b1 ? (sh_b1 << 20) : 1u;

  const f32x4* src = loss4 + (size_t)n * (HWSZ / 4);
  float* cb = cand + (size_t)n * CAND_CAP;
  unsigned stride = gridDim.x * 256;
  for (unsigned i = blockIdx.x * 256 + tid; i < HWSZ / 4; i += stride) {
    f32x4 lv = src[i];
#pragma unroll
    for (int j = 0; j < 4; ++j) {
      unsigned u = __float_as_uint(lv[j]);
      if (u >= thr_u) {
        unsigned idx = atomicAdd(&ctrl->cand_cnt[n], 1u);
        if (idx < CAND_CAP) cb[idx] = lv[j];
      }
    }
  }
}

// ---------- Kernel 5: exact top-128 per sample over candidates + batch mean ----------
__global__ __launch_bounds__(1024) void final_kernel(const float* __restrict__ cand,
                                                     const Ctrl* __restrict__ ctrl,
                                                     float* __restrict__ out) {
  __shared__ unsigned h[4096];
  __shared__ float fs[4096];
  __shared__ float sh_loss[NB];
  __shared__ unsigned sh_bin, sh_cnt, sh_rem;
  __shared__ float sh_sum, sh_tot;
  int tid = threadIdx.x;

  for (int n = 0; n < NB; ++n) {
    unsigned pc = ctrl->cand_cnt[n];
    if (pc > CAND_CAP) pc = CAND_CAP;
    const float* cb = cand + (size_t)n * CAND_CAP;

    if (pc < (unsigned)TOPKK) {
      if (tid == 0) sh_tot = 0.0f;
      __syncthreads();
      float loc = 0.0f;
      for (unsigned i = tid; i < pc; i += 1024) loc += cb[i];
      atomicAdd(&sh_tot, loc);
      __syncthreads();
      if (tid == 0) sh_loss[n] = sh_tot / (float)TOPKK;
      __syncthreads();
      continue;
    }

    // ---- pass 1: top 12 bits ----
    for (int i = tid; i < 4096; i += 1024) { h[i] = 0; fs[i] = 0.0f; }
    __syncthreads();
    for (unsigned i = tid; i < pc; i += 1024) {
      float x = cb[i];
      unsigned u = __float_as_uint(x);
      atomicAdd(&h[u >> 20], 1u);
      atomicAdd(&fs[u >> 20], x);
    }
    __syncthreads();
    if (tid < 64) wave_sel_desc_sh(h, fs, 4096, (unsigned)TOPKK, &sh_bin, &sh_cnt, &sh_sum, &sh_rem);
    __syncthreads();
    unsigned B1 = sh_bin;
    unsigned cnt_gt = sh_cnt;
    float sum_gt = sh_sum;
    unsigned rank = sh_rem;

    // ---- pass 2: mid 12 bits within B1 ----
    for (int i = tid; i < 4096; i += 1024) { h[i] = 0; fs[i] = 0.0f; }
    __syncthreads();
    for (unsigned i = tid; i < pc; i += 1024) {
      float x = cb[i];
      unsigned u = __float_as_uint(x);
      if ((u >> 20) == B1) {
        atomicAdd(&h[(u >> 8) & 0xFFFu], 1u);
        atomicAdd(&fs[(u >> 8) & 0xFFFu], x);
      }
    }
    __syncthreads();
    if (tid < 64) wave_sel_desc_sh(h, fs, 4096, rank, &sh_bin, &sh_cnt, &sh_sum, &sh_rem);
    __syncthreads();
    unsigned B2 = sh_bin;
    cnt_gt += sh_cnt;
    sum_gt += sh_sum;
    rank = sh_rem;
    unsigned pfx = (B1 << 12) | B2;

    // ---- pass 3: low 8 bits within prefix ----
    for (int i = tid; i < 256; i += 1024) { h[i] = 0; fs[i] = 0.0f; }
    __syncthreads();
    for (unsigned i = tid; i < pc; i += 1024) {
      float x = cb[i];
      unsigned u = __float_as_uint(x);
      if ((u >> 8) == pfx) {
        atomicAdd(&h[u & 0xFFu], 1u);
        atomicAdd(&fs[u & 0xFFu], x);
      }
    }
    __syncthreads();
    if (tid < 64) wave_sel_desc_sh(h, fs, 256, rank, &sh_bin, &sh_cnt, &sh_sum, &sh_rem);
    __syncthreads();
    if (tid == 0) {
      unsigned bits = (B1 << 20) | (B2 << 8) | sh_bin;
      float kth = __uint_as_float(bits);
      unsigned cg = cnt_gt + sh_cnt;
      float sg = sum_gt + sh_sum;
      sh_loss[n] = (sg + (float)(TOPKK - (int)cg) * kth) / (float)TOPKK;
    }
    __syncthreads();
  }

  if (tid == 0) {
    float acc = 0.0f;
    for (int i = 0; i < NB; ++i) acc += sh_loss[i];
    out[0] = acc / (float)NB;
  }
}

extern "C" void kernel_launch(void* const* d_in, const int* in_sizes, int n_in,
                              void* d_out, int out_size, void* d_ws, size_t ws_size,
                              hipStream_t stream) {
  (void)in_sizes; (void)n_in; (void)out_size; (void)ws_size;
  const float* pred = (const float*)d_in[0];
  const float* weight = (const float*)d_in[1];
  const int* tgt = (const int*)d_in[2];
  char* ws = (char*)d_ws;
  unsigned* hist1 = (unsigned*)(ws + HIST1_OFF);
  Ctrl*     ctrl  = (Ctrl*)(ws + CTRL_OFF);
  float*    pred_ds = (float*)(ws + PREDDS_OFF);
  float*    loss_full = (float*)(ws + LOSS_OFF);
  float*    cand = (float*)(ws + CAND_OFF);

  hipLaunchKernelGGL(ds_eval, dim3(96, NB), dim3(256), 0, stream,
                     pred, tgt, pred_ds, (float4*)ws);
  hipLaunchKernelGGL(select_ds, dim3(1), dim3(1024), 0, stream, pred_ds, ctrl);
  hipLaunchKernelGGL(main_pass, dim3(NB * SEGS), dim3(256), 0, stream,
                     pred, tgt, weight, ctrl, loss_full, hist1);
  hipLaunchKernelGGL(collect, dim3(72, NB), dim3(256), 0, stream,
                     (const f32x4*)loss_full, hist1, ctrl, cand);
  hipLaunchKernelGGL(final_kernel, dim3(1), dim3(1024), 0, stream,
                     cand, ctrl, (float*)d_out);
}

// Round 7
// 286.917 us; speedup vs baseline: 1.0021x; 1.0021x over previous
//
#include <hip/hip_runtime.h>
#include <math.h>

#define NB 8
#define NC 19
#define HH 768
#define WW 768
#define HWSZ (HH*WW)          // 589824
#define OHH 96
#define OWW 96
#define DSN (NB*OHH*OWW)      // 73728
#define MIN_KEPT_DS 1562
#define TOPKK 128
#define IGNV (-100)
#define SEGS 144              // 4096-px segments per sample

typedef float f32x4 __attribute__((ext_vector_type(4)));
typedef int   i32x4 __attribute__((ext_vector_type(4)));

// ---- workspace layout (bytes) ----
#define HIST1_OFF  0x00000ull      // 8*4096*4 = 131072
#define CTRL_OFF   0x20000ull
#define ZERO_BYTES 0x20400ull      // hist1 + ctrl
#define PREDDS_OFF 0x21000ull      // 73728*4 = 294912 -> ends 0x69000
#define LOSS_OFF   0x70000ull      // 8*589824*4 = 18874368 -> ends 0x1270000
#define CAND_OFF   0x1270000ull    // 8*65536*4 = 2 MB -> total ~21.4 MB
#define CAND_CAP   65536u

struct Ctrl {
  float thr;
  unsigned cand_cnt[NB];
};

// ---- ascending wave select (lanes 0..63): first bin where prefix-count >= rank ----
__device__ __forceinline__ void wave_select_asc(const unsigned* h, int nbins, unsigned rank,
                                                unsigned* out_bin, unsigned* out_rem) {
  int lane = threadIdx.x;
  int ch = nbins >> 6;
  int base = lane * ch;
  unsigned c = 0;
  for (int i = 0; i < ch; ++i) c += h[base + i];
  unsigned s = c;
#pragma unroll
  for (int off = 1; off < 64; off <<= 1) {
    unsigned so = (unsigned)__shfl_up((int)s, off);
    if (lane >= off) s += so;
  }
  unsigned long long ball = __ballot(s >= rank);
  int chunk = (int)__ffsll((unsigned long long)ball) - 1;
  if (lane == chunk) {
    unsigned cum = s - c;
    int bin = base;
    for (int b = base; b < base + ch; ++b) {
      unsigned cc = h[b];
      if (cum + cc >= rank) { bin = b; break; }
      cum += cc;
    }
    *out_bin = (unsigned)bin;
    *out_rem = rank - cum;   // 1-indexed rank within bin
  }
}

// ---- descending wave select with sums (lanes 0..63 of wave 0) ----
__device__ __forceinline__ void wave_sel_desc_sh(const unsigned* h, const float* fs,
                                                 int nbins, unsigned rank,
                                                 unsigned* o_bin, unsigned* o_cnt,
                                                 float* o_sum, unsigned* o_rem) {
  int lane = threadIdx.x;
  int ch = nbins >> 6;
  int base = lane * ch;
  unsigned c = 0; float f = 0.0f;
  for (int i = 0; i < ch; ++i) { c += h[base + i]; f += fs[base + i]; }
  unsigned s = c; float g = f;
#pragma unroll
  for (int off = 1; off < 64; off <<= 1) {
    unsigned so = (unsigned)__shfl_down((int)s, off);
    float go = __shfl_down(g, off);
    if (lane + off < 64) { s += so; g += go; }
  }
  unsigned long long ball = __ballot(s >= rank);
  int chunk = 63 - (int)__clzll(ball | 1ull);
  if (lane == chunk) {
    unsigned cum = s - c;
    float sab = g - f;
    int bin = base;
    for (int b = base + ch - 1; b >= base; --b) {
      unsigned cc = h[b];
      if (cum + cc >= rank) { bin = b; break; }
      cum += cc; sab += fs[b];
    }
    *o_bin = (unsigned)bin;
    *o_cnt = cum;
    *o_sum = sab;
    *o_rem = rank - cum;
  }
}

// ---------- Kernel 1: downsampled true-class prob, row-coalesced (+ ws zero) ----------
__global__ __launch_bounds__(256) void ds_eval(const float* __restrict__ pred,
                                               const int* __restrict__ tgt,
                                               float* __restrict__ pred_ds,
                                               float4* __restrict__ wzero) {
  __shared__ __align__(16) float rowbuf[4][WW];
  __shared__ float vals[192][NC];
  __shared__ float pr[2][192];
  __shared__ int sh_tc[OWW];
  __shared__ unsigned sh_val[OWW];

  int oy = blockIdx.x;
  int n = blockIdx.y;
  int tid = threadIdx.x;
  const float SY = (float)(767.0 / 95.0);

  {
    int blk = n * 96 + oy;
    int nw = (int)(ZERO_BYTES / 16);
    if (tid < 45) {
      int i = blk * 45 + tid;
      if (i < nw) wzero[i] = make_float4(0.f, 0.f, 0.f, 0.f);
    }
  }

  float cy = (float)oy * SY;
  int y0 = (int)floorf(cy);
  int y1 = min(y0 + 1, HH - 1);
  float fy = cy - (float)y0;
  int iy = min((int)floorf(cy + 0.5f), HH - 1);

  if (tid < OWW) {
    float cx = (float)tid * SY;
    int ix = min((int)floorf(cx + 0.5f), WW - 1);
    int t = tgt[(size_t)n * HWSZ + (size_t)iy * WW + ix];
    sh_val[tid] = (t != IGNV);
    sh_tc[tid] = t < 0 ? 0 : (t > (NC - 1) ? (NC - 1) : t);
  }
  __syncthreads();

  const float* base = pred + (size_t)n * NC * HWSZ;
  int rows[2] = { y0, y1 };
#pragma unroll
  for (int r = 0; r < 2; ++r) {
    const float* rbase = base + (size_t)rows[r] * WW;
    for (int c0 = 0; c0 < NC; c0 += 4) {
      int ncc = (NC - c0) < 4 ? (NC - c0) : 4;
      for (int k = tid; k < ncc * 192; k += 256) {
        int cc = k / 192, q = k % 192;
        ((float4*)rowbuf[cc])[q] = ((const float4*)(rbase + (size_t)(c0 + cc) * HWSZ))[q];
      }
      __syncthreads();
      if (tid < 192) {
        int col = min((int)floorf((float)(tid >> 1) * SY) + (tid & 1), WW - 1);
        for (int cc = 0; cc < ncc; ++cc) vals[tid][c0 + cc] = rowbuf[cc][col];
      }
      __syncthreads();
    }
    if (tid < 192) {
      int tc = sh_tc[tid >> 1];
      float m = -INFINITY, lt = 0.0f;
#pragma unroll
      for (int c = 0; c < NC; ++c) m = fmaxf(m, vals[tid][c]);
      float s = 0.0f;
#pragma unroll
      for (int c = 0; c < NC; ++c) {
        float v = vals[tid][c];
        s += expf(v - m);
        lt = (c == tc) ? v : lt;
      }
      pr[r][tid] = expf(lt - m) / s;
    }
    __syncthreads();
  }

  if (tid < OWW) {
    int ox = tid;
    float cx = (float)ox * SY;
    int x0 = (int)floorf(cx);
    float fx = cx - (float)x0;
    float py0 = pr[0][2 * ox] * (1.0f - fy) + pr[1][2 * ox] * fy;
    float py1 = pr[0][2 * ox + 1] * (1.0f - fy) + pr[1][2 * ox + 1] * fy;
    float out = py0 * (1.0f - fx) + py1 * fx;
    pred_ds[(size_t)n * (OHH * OWW) + oy * OWW + ox] = sh_val[ox] ? out : INFINITY;
  }
}

// ---------- Kernel 2: exact kth-smallest of pred_ds -> threshold ----------
__global__ __launch_bounds__(1024) void select_ds(const float* __restrict__ pred_ds,
                                                  Ctrl* ctrl) {
  __shared__ unsigned h[4096];
  __shared__ unsigned sb, srem;
  int tid = threadIdx.x;

  for (int i = tid; i < 4096; i += 1024) h[i] = 0;
  __syncthreads();
  for (int i = tid; i < DSN; i += 1024) {
    unsigned u = __float_as_uint(pred_ds[i]);
    atomicAdd(&h[u >> 20], 1u);
  }
  __syncthreads();
  unsigned nv = DSN - h[0x7F8];
  unsigned kq = nv < (unsigned)MIN_KEPT_DS ? nv : (unsigned)MIN_KEPT_DS;
  unsigned rank = kq > 0 ? kq : 1;
  if (tid < 64) wave_select_asc(h, 4096, rank, &sb, &srem);
  __syncthreads();
  unsigned b1 = sb, rem1 = srem;

  for (int i = tid; i < 4096; i += 1024) h[i] = 0;
  __syncthreads();
  for (int i = tid; i < DSN; i += 1024) {
    unsigned u = __float_as_uint(pred_ds[i]);
    if ((u >> 20) == b1) atomicAdd(&h[(u >> 8) & 0xFFFu], 1u);
  }
  __syncthreads();
  if (tid < 64) wave_select_asc(h, 4096, rem1, &sb, &srem);
  __syncthreads();
  unsigned b2 = sb, rem2 = srem;
  unsigned pfx = (b1 << 12) | b2;

  for (int i = tid; i < 256; i += 1024) h[i] = 0;
  __syncthreads();
  for (int i = tid; i < DSN; i += 1024) {
    unsigned u = __float_as_uint(pred_ds[i]);
    if ((u >> 8) == pfx) atomicAdd(&h[u & 0xFFu], 1u);
  }
  __syncthreads();
  if (tid < 64) wave_select_asc(h, 256, rem2, &sb, &srem);
  __syncthreads();

  if (tid == 0) {
    float kthv = __uint_as_float((pfx << 8) | sb);
    float thr = (kthv > 0.7f) ? kthv : 0.7f;
    if ((unsigned)MIN_KEPT_DS >= nv) thr = 1.0f;
    ctrl->thr = thr;
  }
}

// ---------- Kernel 3: main pass — softmax+NLL -> loss map + fused coarse hist ----------
__global__ __launch_bounds__(256) void main_pass(const float* __restrict__ pred,
                                                 const int* __restrict__ tgt,
                                                 const float* __restrict__ wgt,
                                                 const Ctrl* __restrict__ ctrl,
                                                 float* __restrict__ loss_full,
                                                 unsigned* __restrict__ hist1) {
  __shared__ unsigned h[4096];
  for (int i = threadIdx.x; i < 4096; i += 256) h[i] = 0;
  __syncthreads();

  int blk = blockIdx.x;          // 0..NB*SEGS-1
  int n = blk / SEGS;
  int seg = blk % SEGS;
  const float thr = ctrl->thr;
  const float* basep = pred + (size_t)n * NC * HWSZ;
  const int* tgtb = tgt + (size_t)n * HWSZ;
  float* lossb = loss_full + (size_t)n * HWSZ;

  for (int chunk = 0; chunk < 4; ++chunk) {
    int hw = seg * 4096 + chunk * 1024 + threadIdx.x * 4;

    const f32x4* pb = (const f32x4*)(basep + hw);
    f32x4 v[NC];
#pragma unroll
    for (int c = 0; c < NC; ++c)
      v[c] = pb[(size_t)c * (HWSZ / 4)];     // plain vector load (NT reverted)

    i32x4 t4 = *(const i32x4*)(tgtb + hw);
    int tc[4]; bool val[4]; float m[4], s[4], lt[4];
#pragma unroll
    for (int j = 0; j < 4; ++j) {
      int tv = t4[j];
      val[j] = (tv != IGNV);
      int tcl = tv < 0 ? 0 : (tv > (NC - 1) ? (NC - 1) : tv);
      tc[j] = tcl;
      m[j] = -INFINITY; s[j] = 0.0f; lt[j] = 0.0f;
    }
#pragma unroll
    for (int c = 0; c < NC; ++c) {
#pragma unroll
      for (int j = 0; j < 4; ++j) m[j] = fmaxf(m[j], v[c][j]);
    }
#pragma unroll
    for (int c = 0; c < NC; ++c) {
#pragma unroll
      for (int j = 0; j < 4; ++j) {
        float x = v[c][j];
        s[j] += __expf(x - m[j]);
        lt[j] = (c == tc[j]) ? x : lt[j];
      }
    }

    f32x4 lo;
#pragma unroll
    for (int j = 0; j < 4; ++j) {
      float d = lt[j] - m[j];
      float p = __expf(d) / s[j];
      float logp = d - __logf(s[j]);
      float nll = -logp * wgt[tc[j]];
      float loss = (val[j] && p <= thr) ? nll : 0.0f;
      loss = fmaxf(loss, 0.0f);      // canonicalize -0/neg-ulp -> +0
      lo[j] = loss;
      unsigned u = __float_as_uint(loss);
      if (u) atomicAdd(&h[u >> 20], 1u);
    }
    *(f32x4*)(lossb + hw) = lo;
  }

  __syncthreads();
  for (int i = threadIdx.x; i < 4096; i += 256) {
    unsigned c = h[i];
    if (c) atomicAdd(&hist1[(size_t)n * 4096 + i], c);
  }
}

// ---------- Kernel 4: collect candidates (all losses >= coarse-bin floor) ----------
__global__ __launch_bounds__(256) void collect(const f32x4* __restrict__ loss4,
                                               const unsigned* __restrict__ hist1,
                                               Ctrl* __restrict__ ctrl,
                                               float* __restrict__ cand) {
  __shared__ unsigned sh_b1;
  int n = blockIdx.y;
  int tid = threadIdx.x;

  if (tid < 64) {
    const unsigned* hh = hist1 + (size_t)n * 4096;
    int lane = tid;
    int base = lane * 64;
    unsigned c = 0;
    for (int i = 0; i < 64; ++i) c += hh[base + i];
    unsigned s = c;
#pragma unroll
    for (int off = 1; off < 64; off <<= 1) {
      unsigned so = (unsigned)__shfl_down((int)s, off);
      if (lane + off < 64) s += so;
    }
    unsigned long long ball = __ballot(s >= (unsigned)TOPKK);
    if (ball == 0ull) {
      if (lane == 0) sh_b1 = 0u;       // <128 positives: collect all nonzero
    } else {
      int chunk = 63 - (int)__clzll(ball);
      if (lane == chunk) {
        unsigned cum = s - c;
        int bin = base;
        for (int b = base + 63; b >= base; --b) {
          unsigned cc = hh[b];
          if (cum + cc >= (unsigned)TOPKK) { bin = b; break; }
          cum += cc;
        }
        sh_b1 = (unsigned)bin;
      }
    }
  }
  __syncthreads();
  unsigned thr_u = sh_b1 ? (sh_b1 << 20) : 1u;

  int lane = tid & 63;
  unsigned long long lanelt = (1ull << lane) - 1ull;
  const f32x4* src = loss4 + (size_t)n * (HWSZ / 4);
  float* cb = cand + (size_t)n * CAND_CAP;
  unsigned stride = gridDim.x * 256;
  for (unsigned i = blockIdx.x * 256 + tid; i < HWSZ / 4; i += stride) {
    f32x4 lv = src[i];
#pragma unroll
    for (int j = 0; j < 4; ++j) {
      bool take = (__float_as_uint(lv[j]) >= thr_u);
      unsigned long long mask = __ballot(take);
      if (mask) {
        unsigned cnt = (unsigned)__popcll(mask);
        unsigned wbase = 0;
        if (lane == 0) wbase = atomicAdd(&ctrl->cand_cnt[n], cnt);
        wbase = (unsigned)__shfl((int)wbase, 0);
        if (take) {
          unsigned idx = wbase + (unsigned)__popcll(mask & lanelt);
          if (idx < CAND_CAP) cb[idx] = lv[j];
        }
      }
    }
  }
}

// ---------- Kernel 5: exact top-128 per sample over candidates + batch mean ----------
__global__ __launch_bounds__(1024) void final_kernel(const float* __restrict__ cand,
                                                     const Ctrl* __restrict__ ctrl,
                                                     float* __restrict__ out) {
  __shared__ unsigned h[4096];
  __shared__ float fs[4096];
  __shared__ float sh_loss[NB];
  __shared__ unsigned sh_bin, sh_cnt, sh_rem;
  __shared__ float sh_sum, sh_tot;
  int tid = threadIdx.x;

  for (int n = 0; n < NB; ++n) {
    unsigned pc = ctrl->cand_cnt[n];
    if (pc > CAND_CAP) pc = CAND_CAP;
    const float* cb = cand + (size_t)n * CAND_CAP;

    if (pc < (unsigned)TOPKK) {
      if (tid == 0) sh_tot = 0.0f;
      __syncthreads();
      float loc = 0.0f;
      for (unsigned i = tid; i < pc; i += 1024) loc += cb[i];
      atomicAdd(&sh_tot, loc);
      __syncthreads();
      if (tid == 0) sh_loss[n] = sh_tot / (float)TOPKK;
      __syncthreads();
      continue;
    }

    // ---- pass 1: top 12 bits ----
    for (int i = tid; i < 4096; i += 1024) { h[i] = 0; fs[i] = 0.0f; }
    __syncthreads();
    for (unsigned i = tid; i < pc; i += 1024) {
      float x = cb[i];
      unsigned u = __float_as_uint(x);
      atomicAdd(&h[u >> 20], 1u);
      atomicAdd(&fs[u >> 20], x);
    }
    __syncthreads();
    if (tid < 64) wave_sel_desc_sh(h, fs, 4096, (unsigned)TOPKK, &sh_bin, &sh_cnt, &sh_sum, &sh_rem);
    __syncthreads();
    unsigned B1 = sh_bin;
    unsigned cnt_gt = sh_cnt;
    float sum_gt = sh_sum;
    unsigned rank = sh_rem;

    // ---- pass 2: mid 12 bits within B1 ----
    for (int i = tid; i < 4096; i += 1024) { h[i] = 0; fs[i] = 0.0f; }
    __syncthreads();
    for (unsigned i = tid; i < pc; i += 1024) {
      float x = cb[i];
      unsigned u = __float_as_uint(x);
      if ((u >> 20) == B1) {
        atomicAdd(&h[(u >> 8) & 0xFFFu], 1u);
        atomicAdd(&fs[(u >> 8) & 0xFFFu], x);
      }
    }
    __syncthreads();
    if (tid < 64) wave_sel_desc_sh(h, fs, 4096, rank, &sh_bin, &sh_cnt, &sh_sum, &sh_rem);
    __syncthreads();
    unsigned B2 = sh_bin;
    cnt_gt += sh_cnt;
    sum_gt += sh_sum;
    rank = sh_rem;
    unsigned pfx = (B1 << 12) | B2;

    // ---- pass 3: low 8 bits within prefix ----
    for (int i = tid; i < 256; i += 1024) { h[i] = 0; fs[i] = 0.0f; }
    __syncthreads();
    for (unsigned i = tid; i < pc; i += 1024) {
      float x = cb[i];
      unsigned u = __float_as_uint(x);
      if ((u >> 8) == pfx) {
        atomicAdd(&h[u & 0xFFu], 1u);
        atomicAdd(&fs[u & 0xFFu], x);
      }
    }
    __syncthreads();
    if (tid < 64) wave_sel_desc_sh(h, fs, 256, rank, &sh_bin, &sh_cnt, &sh_sum, &sh_rem);
    __syncthreads();
    if (tid == 0) {
      unsigned bits = (B1 << 20) | (B2 << 8) | sh_bin;
      float kth = __uint_as_float(bits);
      unsigned cg = cnt_gt + sh_cnt;
      float sg = sum_gt + sh_sum;
      sh_loss[n] = (sg + (float)(TOPKK - (int)cg) * kth) / (float)TOPKK;
    }
    __syncthreads();
  }

  if (tid == 0) {
    float acc = 0.0f;
    for (int i = 0; i < NB; ++i) acc += sh_loss[i];
    out[0] = acc / (float)NB;
  }
}

extern "C" void kernel_launch(void* const* d_in, const int* in_sizes, int n_in,
                              void* d_out, int out_size, void* d_ws, size_t ws_size,
                              hipStream_t stream) {
  (void)in_sizes; (void)n_in; (void)out_size; (void)ws_size;
  const float* pred = (const float*)d_in[0];
  const float* weight = (const float*)d_in[1];
  const int* tgt = (const int*)d_in[2];
  char* ws = (char*)d_ws;
  unsigned* hist1 = (unsigned*)(ws + HIST1_OFF);
  Ctrl*     ctrl  = (Ctrl*)(ws + CTRL_OFF);
  float*    pred_ds = (float*)(ws + PREDDS_OFF);
  float*    loss_full = (float*)(ws + LOSS_OFF);
  float*    cand = (float*)(ws + CAND_OFF);

  hipLaunchKernelGGL(ds_eval, dim3(96, NB), dim3(256), 0, stream,
                     pred, tgt, pred_ds, (float4*)ws);
  hipLaunchKernelGGL(select_ds, dim3(1), dim3(1024), 0, stream, pred_ds, ctrl);
  hipLaunchKernelGGL(main_pass, dim3(NB * SEGS), dim3(256), 0, stream,
                     pred, tgt, weight, ctrl, loss_full, hist1);
  hipLaunchKernelGGL(collect, dim3(72, NB), dim3(256), 0, stream,
                     (const f32x4*)loss_full, hist1, ctrl, cand);
  hipLaunchKernelGGL(final_kernel, dim3(1), dim3(1024), 0, stream,
                     cand, ctrl, (float*)d_out);
}

// Round 8
// 286.825 us; speedup vs baseline: 1.0024x; 1.0003x over previous
//
#include <hip/hip_runtime.h>
#include <math.h>

#define NB 8
#define NC 19
#define HH 768
#define WW 768
#define HWSZ (HH*WW)          // 589824
#define OHH 96
#define OWW 96
#define DSN (NB*OHH*OWW)      // 73728
#define MIN_KEPT_DS 1562
#define TOPKK 128
#define IGNV (-100)
#define BLOCKS_PER_SAMPLE 576 // HWSZ / 1024 pixels per block

typedef float f32x4 __attribute__((ext_vector_type(4)));

// ---- workspace layout (bytes) ----
#define HIST1_OFF  0x00000ull      // 8*4096*4 = 131072
#define CTRL_OFF   0x20000ull
#define ZERO_BYTES 0x20400ull      // hist1 + ctrl
#define PREDDS_OFF 0x21000ull      // 73728*4 = 294912 -> ends 0x69000
#define LOSS_OFF   0x70000ull      // 8*589824*4 = 18874368 -> ends 0x1270000
#define CAND_OFF   0x1270000ull    // 8*65536*4 = 2 MB -> total ~21.4 MB
#define CAND_CAP   65536u

struct Ctrl {
  float thr;
  unsigned cand_cnt[NB];
};

__device__ __forceinline__ float fcomp(const float4 a, int j) {
  return (j == 0) ? a.x : (j == 1) ? a.y : (j == 2) ? a.z : a.w;
}

// ---- ascending wave select (lanes 0..63): first bin where prefix-count >= rank ----
__device__ __forceinline__ void wave_select_asc(const unsigned* h, int nbins, unsigned rank,
                                                unsigned* out_bin, unsigned* out_rem) {
  int lane = threadIdx.x;
  int ch = nbins >> 6;
  int base = lane * ch;
  unsigned c = 0;
  for (int i = 0; i < ch; ++i) c += h[base + i];
  unsigned s = c;
#pragma unroll
  for (int off = 1; off < 64; off <<= 1) {
    unsigned so = (unsigned)__shfl_up((int)s, off);
    if (lane >= off) s += so;
  }
  unsigned long long ball = __ballot(s >= rank);
  int chunk = (int)__ffsll((unsigned long long)ball) - 1;
  if (lane == chunk) {
    unsigned cum = s - c;
    int bin = base;
    for (int b = base; b < base + ch; ++b) {
      unsigned cc = h[b];
      if (cum + cc >= rank) { bin = b; break; }
      cum += cc;
    }
    *out_bin = (unsigned)bin;
    *out_rem = rank - cum;   // 1-indexed rank within bin
  }
}

// ---- descending wave select with sums (lanes 0..63 of wave 0) ----
__device__ __forceinline__ void wave_sel_desc_sh(const unsigned* h, const float* fs,
                                                 int nbins, unsigned rank,
                                                 unsigned* o_bin, unsigned* o_cnt,
                                                 float* o_sum, unsigned* o_rem) {
  int lane = threadIdx.x;
  int ch = nbins >> 6;
  int base = lane * ch;
  unsigned c = 0; float f = 0.0f;
  for (int i = 0; i < ch; ++i) { c += h[base + i]; f += fs[base + i]; }
  unsigned s = c; float g = f;
#pragma unroll
  for (int off = 1; off < 64; off <<= 1) {
    unsigned so = (unsigned)__shfl_down((int)s, off);
    float go = __shfl_down(g, off);
    if (lane + off < 64) { s += so; g += go; }
  }
  unsigned long long ball = __ballot(s >= rank);
  int chunk = 63 - (int)__clzll(ball | 1ull);
  if (lane == chunk) {
    unsigned cum = s - c;
    float sab = g - f;
    int bin = base;
    for (int b = base + ch - 1; b >= base; --b) {
      unsigned cc = h[b];
      if (cum + cc >= rank) { bin = b; break; }
      cum += cc; sab += fs[b];
    }
    *o_bin = (unsigned)bin;
    *o_cnt = cum;
    *o_sum = sab;
    *o_rem = rank - cum;
  }
}

// ---------- Kernel 1: downsampled true-class prob, row-coalesced (+ ws zero) ----------
// BYTE-IDENTICAL structure to the 195us Round-5 version.
__global__ __launch_bounds__(256) void ds_eval(const float* __restrict__ pred,
                                               const int* __restrict__ tgt,
                                               float* __restrict__ pred_ds,
                                               float4* __restrict__ wzero) {
  __shared__ __align__(16) float rowbuf[4][WW];
  __shared__ float vals[192][NC];
  __shared__ float pr[2][192];
  __shared__ int sh_tc[OWW];
  __shared__ unsigned sh_val[OWW];

  int oy = blockIdx.x;
  int n = blockIdx.y;
  int tid = threadIdx.x;
  const float SY = (float)(767.0 / 95.0);

  {
    int blk = n * 96 + oy;
    int nw = (int)(ZERO_BYTES / 16);
    if (tid < 45) {
      int i = blk * 45 + tid;
      if (i < nw) wzero[i] = make_float4(0.f, 0.f, 0.f, 0.f);
    }
  }

  float cy = (float)oy * SY;
  int y0 = (int)floorf(cy);
  int y1 = min(y0 + 1, HH - 1);
  float fy = cy - (float)y0;
  int iy = min((int)floorf(cy + 0.5f), HH - 1);

  if (tid < OWW) {
    float cx = (float)tid * SY;
    int ix = min((int)floorf(cx + 0.5f), WW - 1);
    int t = tgt[(size_t)n * HWSZ + (size_t)iy * WW + ix];
    sh_val[tid] = (t != IGNV);
    sh_tc[tid] = t < 0 ? 0 : (t > (NC - 1) ? (NC - 1) : t);
  }
  __syncthreads();

  const float* base = pred + (size_t)n * NC * HWSZ;
  int rows[2] = { y0, y1 };
#pragma unroll
  for (int r = 0; r < 2; ++r) {
    const float* rbase = base + (size_t)rows[r] * WW;
    for (int c0 = 0; c0 < NC; c0 += 4) {
      int ncc = (NC - c0) < 4 ? (NC - c0) : 4;
      for (int k = tid; k < ncc * 192; k += 256) {
        int cc = k / 192, q = k % 192;
        ((float4*)rowbuf[cc])[q] = ((const float4*)(rbase + (size_t)(c0 + cc) * HWSZ))[q];
      }
      __syncthreads();
      if (tid < 192) {
        int col = min((int)floorf((float)(tid >> 1) * SY) + (tid & 1), WW - 1);
        for (int cc = 0; cc < ncc; ++cc) vals[tid][c0 + cc] = rowbuf[cc][col];
      }
      __syncthreads();
    }
    if (tid < 192) {
      int tc = sh_tc[tid >> 1];
      float m = -INFINITY, lt = 0.0f;
#pragma unroll
      for (int c = 0; c < NC; ++c) m = fmaxf(m, vals[tid][c]);
      float s = 0.0f;
#pragma unroll
      for (int c = 0; c < NC; ++c) {
        float v = vals[tid][c];
        s += expf(v - m);
        lt = (c == tc) ? v : lt;
      }
      pr[r][tid] = expf(lt - m) / s;
    }
    __syncthreads();
  }

  if (tid < OWW) {
    int ox = tid;
    float cx = (float)ox * SY;
    int x0 = (int)floorf(cx);
    float fx = cx - (float)x0;
    float py0 = pr[0][2 * ox] * (1.0f - fy) + pr[1][2 * ox] * fy;
    float py1 = pr[0][2 * ox + 1] * (1.0f - fy) + pr[1][2 * ox + 1] * fy;
    float out = py0 * (1.0f - fx) + py1 * fx;
    pred_ds[(size_t)n * (OHH * OWW) + oy * OWW + ox] = sh_val[ox] ? out : INFINITY;
  }
}

// ---------- Kernel 2: exact kth-smallest of pred_ds -> threshold ----------
__global__ __launch_bounds__(1024) void select_ds(const float* __restrict__ pred_ds,
                                                  Ctrl* ctrl) {
  __shared__ unsigned h[4096];
  __shared__ unsigned sb, srem;
  int tid = threadIdx.x;

  for (int i = tid; i < 4096; i += 1024) h[i] = 0;
  __syncthreads();
  for (int i = tid; i < DSN; i += 1024) {
    unsigned u = __float_as_uint(pred_ds[i]);
    atomicAdd(&h[u >> 20], 1u);
  }
  __syncthreads();
  unsigned nv = DSN - h[0x7F8];
  unsigned kq = nv < (unsigned)MIN_KEPT_DS ? nv : (unsigned)MIN_KEPT_DS;
  unsigned rank = kq > 0 ? kq : 1;
  if (tid < 64) wave_select_asc(h, 4096, rank, &sb, &srem);
  __syncthreads();
  unsigned b1 = sb, rem1 = srem;

  for (int i = tid; i < 4096; i += 1024) h[i] = 0;
  __syncthreads();
  for (int i = tid; i < DSN; i += 1024) {
    unsigned u = __float_as_uint(pred_ds[i]);
    if ((u >> 20) == b1) atomicAdd(&h[(u >> 8) & 0xFFFu], 1u);
  }
  __syncthreads();
  if (tid < 64) wave_select_asc(h, 4096, rem1, &sb, &srem);
  __syncthreads();
  unsigned b2 = sb, rem2 = srem;
  unsigned pfx = (b1 << 12) | b2;

  for (int i = tid; i < 256; i += 1024) h[i] = 0;
  __syncthreads();
  for (int i = tid; i < DSN; i += 1024) {
    unsigned u = __float_as_uint(pred_ds[i]);
    if ((u >> 8) == pfx) atomicAdd(&h[u & 0xFFu], 1u);
  }
  __syncthreads();
  if (tid < 64) wave_select_asc(h, 256, rem2, &sb, &srem);
  __syncthreads();

  if (tid == 0) {
    float kthv = __uint_as_float((pfx << 8) | sb);
    float thr = (kthv > 0.7f) ? kthv : 0.7f;
    if ((unsigned)MIN_KEPT_DS >= nv) thr = 1.0f;
    ctrl->thr = thr;
  }
}

// ---------- Kernel 3: main pass — softmax+NLL -> loss map (pure streaming) ----------
// BYTE-IDENTICAL to the 195us Round-5 version (576 blocks/sample, 1024 px/block).
__global__ __launch_bounds__(256) void main_pass(const float* __restrict__ pred,
                                                 const int* __restrict__ tgt,
                                                 const float* __restrict__ wgt,
                                                 const Ctrl* __restrict__ ctrl,
                                                 float* __restrict__ loss_full) {
  int n = blockIdx.x / BLOCKS_PER_SAMPLE;
  int hw = (blockIdx.x % BLOCKS_PER_SAMPLE) * 1024 + threadIdx.x * 4;
  const float thr = ctrl->thr;

  const float4* pb = (const float4*)(pred + (size_t)n * NC * HWSZ + hw);
  float4 v[NC];
#pragma unroll
  for (int c = 0; c < NC; ++c) v[c] = pb[(size_t)c * (HWSZ / 4)];

  int4 t4 = *(const int4*)(tgt + (size_t)n * HWSZ + hw);
  int tv[4] = { t4.x, t4.y, t4.z, t4.w };
  int tc[4]; bool val[4]; float m[4], s[4], lt[4];
#pragma unroll
  for (int j = 0; j < 4; ++j) {
    val[j] = (tv[j] != IGNV);
    int tcl = tv[j] < 0 ? 0 : (tv[j] > (NC - 1) ? (NC - 1) : tv[j]);
    tc[j] = tcl;
    m[j] = -INFINITY; s[j] = 0.0f; lt[j] = 0.0f;
  }
#pragma unroll
  for (int c = 0; c < NC; ++c) {
#pragma unroll
    for (int j = 0; j < 4; ++j) m[j] = fmaxf(m[j], fcomp(v[c], j));
  }
#pragma unroll
  for (int c = 0; c < NC; ++c) {
#pragma unroll
    for (int j = 0; j < 4; ++j) {
      float x = fcomp(v[c], j);
      s[j] += __expf(x - m[j]);
      lt[j] = (c == tc[j]) ? x : lt[j];
    }
  }

  float4 lo;
  float* lop = (float*)&lo;
#pragma unroll
  for (int j = 0; j < 4; ++j) {
    float d = lt[j] - m[j];
    float p = __expf(d) / s[j];
    float logp = d - __logf(s[j]);
    float nll = -logp * wgt[tc[j]];
    float loss = (val[j] && p <= thr) ? nll : 0.0f;
    lop[j] = fmaxf(loss, 0.0f);
  }
  *(float4*)(loss_full + (size_t)n * HWSZ + hw) = lo;
}

// ---------- Kernel 4: per-sample coarse 12-bit hist (counts only, zeros skipped) ----------
__global__ __launch_bounds__(256) void hist_pass(const f32x4* __restrict__ loss4,
                                                 unsigned* __restrict__ hist1) {
  __shared__ unsigned h[4096];
  int n = blockIdx.y;
  int tid = threadIdx.x;
  for (int i = tid; i < 4096; i += 256) h[i] = 0;
  __syncthreads();
  const f32x4* src = loss4 + (size_t)n * (HWSZ / 4);
  unsigned stride = gridDim.x * 256;
  for (unsigned i = blockIdx.x * 256 + tid; i < HWSZ / 4; i += stride) {
    f32x4 lv = src[i];
#pragma unroll
    for (int j = 0; j < 4; ++j) {
      unsigned u = __float_as_uint(lv[j]);
      if (u) atomicAdd(&h[u >> 20], 1u);
    }
  }
  __syncthreads();
  for (int i = tid; i < 4096; i += 256) {
    unsigned c = h[i];
    if (c) atomicAdd(&hist1[(size_t)n * 4096 + i], c);
  }
}

// ---------- Kernel 5: collect candidates (all losses >= coarse-bin floor) ----------
__global__ __launch_bounds__(256) void collect(const f32x4* __restrict__ loss4,
                                               const unsigned* __restrict__ hist1,
                                               Ctrl* __restrict__ ctrl,
                                               float* __restrict__ cand) {
  __shared__ unsigned sh_b1;
  int n = blockIdx.y;
  int tid = threadIdx.x;

  if (tid < 64) {
    const unsigned* hh = hist1 + (size_t)n * 4096;
    int lane = tid;
    int base = lane * 64;
    unsigned c = 0;
    for (int i = 0; i < 64; ++i) c += hh[base + i];
    unsigned s = c;
#pragma unroll
    for (int off = 1; off < 64; off <<= 1) {
      unsigned so = (unsigned)__shfl_down((int)s, off);
      if (lane + off < 64) s += so;
    }
    unsigned long long ball = __ballot(s >= (unsigned)TOPKK);
    if (ball == 0ull) {
      if (lane == 0) sh_b1 = 0u;       // <128 positives: collect all nonzero
    } else {
      int chunk = 63 - (int)__clzll(ball);
      if (lane == chunk) {
        unsigned cum = s - c;
        int bin = base;
        for (int b = base + 63; b >= base; --b) {
          unsigned cc = hh[b];
          if (cum + cc >= (unsigned)TOPKK) { bin = b; break; }
          cum += cc;
        }
        sh_b1 = (unsigned)bin;
      }
    }
  }
  __syncthreads();
  unsigned thr_u = sh_b1 ? (sh_b1 << 20) : 1u;

  int lane = tid & 63;
  unsigned long long lanelt = (1ull << lane) - 1ull;
  const f32x4* src = loss4 + (size_t)n * (HWSZ / 4);
  float* cb = cand + (size_t)n * CAND_CAP;
  unsigned stride = gridDim.x * 256;
  for (unsigned i = blockIdx.x * 256 + tid; i < HWSZ / 4; i += stride) {
    f32x4 lv = src[i];
#pragma unroll
    for (int j = 0; j < 4; ++j) {
      bool take = (__float_as_uint(lv[j]) >= thr_u);
      unsigned long long mask = __ballot(take);
      if (mask) {
        unsigned cnt = (unsigned)__popcll(mask);
        unsigned wbase = 0;
        if (lane == 0) wbase = atomicAdd(&ctrl->cand_cnt[n], cnt);
        wbase = (unsigned)__shfl((int)wbase, 0);
        if (take) {
          unsigned idx = wbase + (unsigned)__popcll(mask & lanelt);
          if (idx < CAND_CAP) cb[idx] = lv[j];
        }
      }
    }
  }
}

// ---------- Kernel 6: exact top-128 per sample over candidates + batch mean ----------
__global__ __launch_bounds__(1024) void final_kernel(const float* __restrict__ cand,
                                                     const Ctrl* __restrict__ ctrl,
                                                     float* __restrict__ out) {
  __shared__ unsigned h[4096];
  __shared__ float fs[4096];
  __shared__ float sh_loss[NB];
  __shared__ unsigned sh_bin, sh_cnt, sh_rem;
  __shared__ float sh_sum, sh_tot;
  int tid = threadIdx.x;

  for (int n = 0; n < NB; ++n) {
    unsigned pc = ctrl->cand_cnt[n];
    if (pc > CAND_CAP) pc = CAND_CAP;
    const float* cb = cand + (size_t)n * CAND_CAP;

    if (pc < (unsigned)TOPKK) {
      if (tid == 0) sh_tot = 0.0f;
      __syncthreads();
      float loc = 0.0f;
      for (unsigned i = tid; i < pc; i += 1024) loc += cb[i];
      atomicAdd(&sh_tot, loc);
      __syncthreads();
      if (tid == 0) sh_loss[n] = sh_tot / (float)TOPKK;
      __syncthreads();
      continue;
    }

    // ---- pass 1: top 12 bits ----
    for (int i = tid; i < 4096; i += 1024) { h[i] = 0; fs[i] = 0.0f; }
    __syncthreads();
    for (unsigned i = tid; i < pc; i += 1024) {
      float x = cb[i];
      unsigned u = __float_as_uint(x);
      atomicAdd(&h[u >> 20], 1u);
      atomicAdd(&fs[u >> 20], x);
    }
    __syncthreads();
    if (tid < 64) wave_sel_desc_sh(h, fs, 4096, (unsigned)TOPKK, &sh_bin, &sh_cnt, &sh_sum, &sh_rem);
    __syncthreads();
    unsigned B1 = sh_bin;
    unsigned cnt_gt = sh_cnt;
    float sum_gt = sh_sum;
    unsigned rank = sh_rem;

    // ---- pass 2: mid 12 bits within B1 ----
    for (int i = tid; i < 4096; i += 1024) { h[i] = 0; fs[i] = 0.0f; }
    __syncthreads();
    for (unsigned i = tid; i < pc; i += 1024) {
      float x = cb[i];
      unsigned u = __float_as_uint(x);
      if ((u >> 20) == B1) {
        atomicAdd(&h[(u >> 8) & 0xFFFu], 1u);
        atomicAdd(&fs[(u >> 8) & 0xFFFu], x);
      }
    }
    __syncthreads();
    if (tid < 64) wave_sel_desc_sh(h, fs, 4096, rank, &sh_bin, &sh_cnt, &sh_sum, &sh_rem);
    __syncthreads();
    unsigned B2 = sh_bin;
    cnt_gt += sh_cnt;
    sum_gt += sh_sum;
    rank = sh_rem;
    unsigned pfx = (B1 << 12) | B2;

    // ---- pass 3: low 8 bits within prefix ----
    for (int i = tid; i < 256; i += 1024) { h[i] = 0; fs[i] = 0.0f; }
    __syncthreads();
    for (unsigned i = tid; i < pc; i += 1024) {
      float x = cb[i];
      unsigned u = __float_as_uint(x);
      if ((u >> 8) == pfx) {
        atomicAdd(&h[u & 0xFFu], 1u);
        atomicAdd(&fs[u & 0xFFu], x);
      }
    }
    __syncthreads();
    if (tid < 64) wave_sel_desc_sh(h, fs, 256, rank, &sh_bin, &sh_cnt, &sh_sum, &sh_rem);
    __syncthreads();
    if (tid == 0) {
      unsigned bits = (B1 << 20) | (B2 << 8) | sh_bin;
      float kth = __uint_as_float(bits);
      unsigned cg = cnt_gt + sh_cnt;
      float sg = sum_gt + sh_sum;
      sh_loss[n] = (sg + (float)(TOPKK - (int)cg) * kth) / (float)TOPKK;
    }
    __syncthreads();
  }

  if (tid == 0) {
    float acc = 0.0f;
    for (int i = 0; i < NB; ++i) acc += sh_loss[i];
    out[0] = acc / (float)NB;
  }
}

extern "C" void kernel_launch(void* const* d_in, const int* in_sizes, int n_in,
                              void* d_out, int out_size, void* d_ws, size_t ws_size,
                              hipStream_t stream) {
  (void)in_sizes; (void)n_in; (void)out_size; (void)ws_size;
  const float* pred = (const float*)d_in[0];
  const float* weight = (const float*)d_in[1];
  const int* tgt = (const int*)d_in[2];
  char* ws = (char*)d_ws;
  unsigned* hist1 = (unsigned*)(ws + HIST1_OFF);
  Ctrl*     ctrl  = (Ctrl*)(ws + CTRL_OFF);
  float*    pred_ds = (float*)(ws + PREDDS_OFF);
  float*    loss_full = (float*)(ws + LOSS_OFF);
  float*    cand = (float*)(ws + CAND_OFF);

  hipLaunchKernelGGL(ds_eval, dim3(96, NB), dim3(256), 0, stream,
                     pred, tgt, pred_ds, (float4*)ws);
  hipLaunchKernelGGL(select_ds, dim3(1), dim3(1024), 0, stream, pred_ds, ctrl);
  hipLaunchKernelGGL(main_pass, dim3(NB * BLOCKS_PER_SAMPLE), dim3(256), 0, stream,
                     pred, tgt, weight, ctrl, loss_full);
  hipLaunchKernelGGL(hist_pass, dim3(32, NB), dim3(256), 0, stream,
                     (const f32x4*)loss_full, hist1);
  hipLaunchKernelGGL(collect, dim3(72, NB), dim3(256), 0, stream,
                     (const f32x4*)loss_full, hist1, ctrl, cand);
  hipLaunchKernelGGL(final_kernel, dim3(1), dim3(1024), 0, stream,
                     cand, ctrl, (float*)d_out);
}

// Round 9
// 194.794 us; speedup vs baseline: 1.4760x; 1.4725x over previous
//
#include <hip/hip_runtime.h>
#include <math.h>

#define NB 8
#define NC 19
#define HH 768
#define WW 768
#define HWSZ (HH*WW)          // 589824
#define OHH 96
#define OWW 96
#define DSN (NB*OHH*OWW)      // 73728
#define MIN_KEPT_DS 1562
#define TOPKK 128
#define IGNV (-100)
#define BLOCKS_PER_SAMPLE 576 // HWSZ / 1024 pixels per block

// ---- workspace layout (bytes) ----
#define HIST1_OFF  0x00000ull   // 8*4096*4 = 131072
#define SUM1_OFF   0x20000ull
#define HIST2_OFF  0x40000ull
#define SUM2_OFF   0x60000ull
#define HIST3_OFF  0x80000ull   // 8*256*4 = 8192
#define SUM3_OFF   0x82000ull
#define CTRL_OFF   0x84000ull
#define ZERO_BYTES 0x84400ull   // 541696 (multiple of 16)
#define PREDDS_OFF 0x85000ull   // 73728*4 = 294912
#define LOSS_OFF   0xD0000ull   // 8*589824*4 = 18874368

struct Ctrl {
  float thr;
  unsigned b1[NB], b2[NB], rankv[NB], cnt_gt[NB];
  float sum_gt[NB];
  float sample_loss[NB];
};

__device__ __forceinline__ float fcomp(const float4 a, int j) {
  return (j == 0) ? a.x : (j == 1) ? a.y : (j == 2) ? a.z : a.w;
}

// ---- ascending wave select (lanes 0..63): first bin where prefix-count >= rank ----
__device__ __forceinline__ void wave_select_asc(const unsigned* h, int nbins, unsigned rank,
                                                unsigned* out_bin, unsigned* out_rem) {
  int lane = threadIdx.x;
  int ch = nbins >> 6;
  int base = lane * ch;
  unsigned c = 0;
  for (int i = 0; i < ch; ++i) c += h[base + i];
  unsigned s = c;
#pragma unroll
  for (int off = 1; off < 64; off <<= 1) {
    unsigned so = (unsigned)__shfl_up((int)s, off);
    if (lane >= off) s += so;
  }
  unsigned long long ball = __ballot(s >= rank);
  int chunk = (int)__ffsll((unsigned long long)ball) - 1;
  if (lane == chunk) {
    unsigned cum = s - c;
    int bin = base;
    for (int b = base; b < base + ch; ++b) {
      unsigned cc = h[b];
      if (cum + cc >= rank) { bin = b; break; }
      cum += cc;
    }
    *out_bin = (unsigned)bin;
    *out_rem = rank - cum;   // 1-indexed rank within bin
  }
}

// ---------- Kernel 1: downsampled true-class prob, row-coalesced (+ ws zero) ----------
__global__ __launch_bounds__(256) void ds_eval(const float* __restrict__ pred,
                                               const int* __restrict__ tgt,
                                               float* __restrict__ pred_ds,
                                               float4* __restrict__ wzero) {
  __shared__ __align__(16) float rowbuf[4][WW];
  __shared__ float vals[192][NC];
  __shared__ float pr[2][192];
  __shared__ int sh_tc[OWW];
  __shared__ unsigned sh_val[OWW];

  int oy = blockIdx.x;
  int n = blockIdx.y;
  int tid = threadIdx.x;
  const float SY = (float)(767.0 / 95.0);

  {
    int blk = n * 96 + oy;
    int nw = (int)(ZERO_BYTES / 16);
    if (tid < 45) {
      int i = blk * 45 + tid;
      if (i < nw) wzero[i] = make_float4(0.f, 0.f, 0.f, 0.f);
    }
  }

  float cy = (float)oy * SY;
  int y0 = (int)floorf(cy);
  int y1 = min(y0 + 1, HH - 1);
  float fy = cy - (float)y0;
  int iy = min((int)floorf(cy + 0.5f), HH - 1);

  if (tid < OWW) {
    float cx = (float)tid * SY;
    int ix = min((int)floorf(cx + 0.5f), WW - 1);
    int t = tgt[(size_t)n * HWSZ + (size_t)iy * WW + ix];
    sh_val[tid] = (t != IGNV);
    sh_tc[tid] = t < 0 ? 0 : (t > (NC - 1) ? (NC - 1) : t);
  }
  __syncthreads();

  const float* base = pred + (size_t)n * NC * HWSZ;
  int rows[2] = { y0, y1 };
#pragma unroll
  for (int r = 0; r < 2; ++r) {
    const float* rbase = base + (size_t)rows[r] * WW;
    for (int c0 = 0; c0 < NC; c0 += 4) {
      int ncc = (NC - c0) < 4 ? (NC - c0) : 4;
      for (int k = tid; k < ncc * 192; k += 256) {
        int cc = k / 192, q = k % 192;
        ((float4*)rowbuf[cc])[q] = ((const float4*)(rbase + (size_t)(c0 + cc) * HWSZ))[q];
      }
      __syncthreads();
      if (tid < 192) {
        int col = min((int)floorf((float)(tid >> 1) * SY) + (tid & 1), WW - 1);
        for (int cc = 0; cc < ncc; ++cc) vals[tid][c0 + cc] = rowbuf[cc][col];
      }
      __syncthreads();
    }
    if (tid < 192) {
      int tc = sh_tc[tid >> 1];
      float m = -INFINITY, lt = 0.0f;
#pragma unroll
      for (int c = 0; c < NC; ++c) m = fmaxf(m, vals[tid][c]);
      float s = 0.0f;
#pragma unroll
      for (int c = 0; c < NC; ++c) {
        float v = vals[tid][c];
        s += expf(v - m);
        lt = (c == tc) ? v : lt;
      }
      pr[r][tid] = expf(lt - m) / s;
    }
    __syncthreads();
  }

  if (tid < OWW) {
    int ox = tid;
    float cx = (float)ox * SY;
    int x0 = (int)floorf(cx);
    float fx = cx - (float)x0;
    float py0 = pr[0][2 * ox] * (1.0f - fy) + pr[1][2 * ox] * fy;
    float py1 = pr[0][2 * ox + 1] * (1.0f - fy) + pr[1][2 * ox + 1] * fy;
    float out = py0 * (1.0f - fx) + py1 * fx;
    pred_ds[(size_t)n * (OHH * OWW) + oy * OWW + ox] = sh_val[ox] ? out : INFINITY;
  }
}

// ---------- Kernel 2: exact kth-smallest of pred_ds -> threshold ----------
__global__ __launch_bounds__(1024) void select_ds(const float* __restrict__ pred_ds,
                                                  Ctrl* ctrl) {
  __shared__ unsigned h[4096];
  __shared__ unsigned sb, srem;
  int tid = threadIdx.x;

  for (int i = tid; i < 4096; i += 1024) h[i] = 0;
  __syncthreads();
  for (int i = tid; i < DSN; i += 1024) {
    unsigned u = __float_as_uint(pred_ds[i]);
    atomicAdd(&h[u >> 20], 1u);
  }
  __syncthreads();
  unsigned nv = DSN - h[0x7F8];
  unsigned kq = nv < (unsigned)MIN_KEPT_DS ? nv : (unsigned)MIN_KEPT_DS;
  unsigned rank = kq > 0 ? kq : 1;
  if (tid < 64) wave_select_asc(h, 4096, rank, &sb, &srem);
  __syncthreads();
  unsigned b1 = sb, rem1 = srem;

  for (int i = tid; i < 4096; i += 1024) h[i] = 0;
  __syncthreads();
  for (int i = tid; i < DSN; i += 1024) {
    unsigned u = __float_as_uint(pred_ds[i]);
    if ((u >> 20) == b1) atomicAdd(&h[(u >> 8) & 0xFFFu], 1u);
  }
  __syncthreads();
  if (tid < 64) wave_select_asc(h, 4096, rem1, &sb, &srem);
  __syncthreads();
  unsigned b2 = sb, rem2 = srem;
  unsigned pfx = (b1 << 12) | b2;

  for (int i = tid; i < 256; i += 1024) h[i] = 0;
  __syncthreads();
  for (int i = tid; i < DSN; i += 1024) {
    unsigned u = __float_as_uint(pred_ds[i]);
    if ((u >> 8) == pfx) atomicAdd(&h[u & 0xFFu], 1u);
  }
  __syncthreads();
  if (tid < 64) wave_select_asc(h, 256, rem2, &sb, &srem);
  __syncthreads();

  if (tid == 0) {
    float kthv = __uint_as_float((pfx << 8) | sb);
    float thr = (kthv > 0.7f) ? kthv : 0.7f;
    if ((unsigned)MIN_KEPT_DS >= nv) thr = 1.0f;
    ctrl->thr = thr;
  }
}

// ---------- Kernel 3: main pass — softmax+NLL -> loss map (pure streaming) ----------
__global__ __launch_bounds__(256) void main_pass(const float* __restrict__ pred,
                                                 const int* __restrict__ tgt,
                                                 const float* __restrict__ wgt,
                                                 const Ctrl* __restrict__ ctrl,
                                                 float* __restrict__ loss_full) {
  int n = blockIdx.x / BLOCKS_PER_SAMPLE;
  int hw = (blockIdx.x % BLOCKS_PER_SAMPLE) * 1024 + threadIdx.x * 4;
  const float thr = ctrl->thr;

  const float4* pb = (const float4*)(pred + (size_t)n * NC * HWSZ + hw);
  float4 v[NC];
#pragma unroll
  for (int c = 0; c < NC; ++c) v[c] = pb[(size_t)c * (HWSZ / 4)];

  int4 t4 = *(const int4*)(tgt + (size_t)n * HWSZ + hw);
  int tv[4] = { t4.x, t4.y, t4.z, t4.w };
  int tc[4]; bool val[4]; float m[4], s[4], lt[4];
#pragma unroll
  for (int j = 0; j < 4; ++j) {
    val[j] = (tv[j] != IGNV);
    int tcl = tv[j] < 0 ? 0 : (tv[j] > (NC - 1) ? (NC - 1) : tv[j]);
    tc[j] = tcl;
    m[j] = -INFINITY; s[j] = 0.0f; lt[j] = 0.0f;
  }
#pragma unroll
  for (int c = 0; c < NC; ++c) {
#pragma unroll
    for (int j = 0; j < 4; ++j) m[j] = fmaxf(m[j], fcomp(v[c], j));
  }
#pragma unroll
  for (int c = 0; c < NC; ++c) {
#pragma unroll
    for (int j = 0; j < 4; ++j) {
      float x = fcomp(v[c], j);
      s[j] += __expf(x - m[j]);
      lt[j] = (c == tc[j]) ? x : lt[j];
    }
  }

  float4 lo;
  float* lop = (float*)&lo;
#pragma unroll
  for (int j = 0; j < 4; ++j) {
    float d = lt[j] - m[j];
    float p = __expf(d) / s[j];
    float logp = d - __logf(s[j]);
    float nll = -logp * wgt[tc[j]];
    float loss = (val[j] && p <= thr) ? nll : 0.0f;
    lop[j] = fmaxf(loss, 0.0f);
  }
  *(float4*)(loss_full + (size_t)n * HWSZ + hw) = lo;
}

// ---------- Kernel 4: per-sample coarse 12-bit hist (count+sum), zeros skipped ----------
__global__ __launch_bounds__(256) void hist_pass(const float4* __restrict__ loss4,
                                                 unsigned* __restrict__ hist1,
                                                 float* __restrict__ sum1) {
  __shared__ unsigned h[4096];
  __shared__ float fs[4096];
  int n = blockIdx.y;
  int tid = threadIdx.x;
  for (int i = tid; i < 4096; i += 256) { h[i] = 0; fs[i] = 0.0f; }
  __syncthreads();
  const float4* src = loss4 + (size_t)n * (HWSZ / 4);
  unsigned stride = gridDim.x * 256;
  for (unsigned i = blockIdx.x * 256 + tid; i < HWSZ / 4; i += stride) {
    float4 lv = src[i];
    const float* lp = (const float*)&lv;
#pragma unroll
    for (int j = 0; j < 4; ++j) {
      unsigned u = __float_as_uint(lp[j]);
      if (u) {
        atomicAdd(&h[u >> 20], 1u);
        atomicAdd(&fs[u >> 20], lp[j]);
      }
    }
  }
  __syncthreads();
  for (int i = tid; i < 4096; i += 256) {
    unsigned c = h[i];
    if (c) {
      atomicAdd(&hist1[(size_t)n * 4096 + i], c);
      atomicAdd(&sum1[(size_t)n * 4096 + i], fs[i]);
    }
  }
}

// ---------- Kernel 5/7: descending wave select over 4096-bin global hist ----------
__global__ __launch_bounds__(64) void select_level(const unsigned* __restrict__ hist,
                                                   const float* __restrict__ sums,
                                                   Ctrl* __restrict__ ctrl, int level) {
  int n = blockIdx.x;
  int lane = threadIdx.x;
  if (level == 2 && ctrl->b1[n] > 4095u) return;   // sentinel: already resolved
  const unsigned* h = hist + (size_t)n * 4096;
  const float* fs = sums + (size_t)n * 4096;
  unsigned rank = (level == 1) ? (unsigned)TOPKK : ctrl->rankv[n];
  int base = lane * 64;
  unsigned c = 0; float f = 0.0f;
  for (int i = 0; i < 64; ++i) { c += h[base + i]; f += fs[base + i]; }
  unsigned s = c; float g = f;
#pragma unroll
  for (int off = 1; off < 64; off <<= 1) {
    unsigned so = (unsigned)__shfl_down((int)s, off);
    float go = __shfl_down(g, off);
    if (lane + off < 64) { s += so; g += go; }
  }
  unsigned long long ball = __ballot(s >= rank);
  if (ball == 0ull) {
    // fewer than `rank` nonzero losses total: top-128 = all positives (+ zero pad)
    if (level == 1 && lane == 0) {
      ctrl->sample_loss[n] = g / (float)TOPKK;
      ctrl->b1[n] = 0xFFFFFFFFu;
    }
    return;
  }
  int chunk = 63 - (int)__clzll((unsigned long long)ball);
  if (lane == chunk) {
    unsigned cum = s - c;
    float sab = g - f;
    int bin = base;
    for (int b = base + 63; b >= base; --b) {
      unsigned cc = h[b];
      if (cum + cc >= rank) { bin = b; break; }
      cum += cc; sab += fs[b];
    }
    if (level == 1) {
      ctrl->b1[n] = (unsigned)bin;
      ctrl->cnt_gt[n] = cum;
      ctrl->sum_gt[n] = sab;
    } else {
      ctrl->b2[n] = (unsigned)bin;
      ctrl->cnt_gt[n] += cum;
      ctrl->sum_gt[n] += sab;
    }
    ctrl->rankv[n] = rank - cum;
  }
}

// ---------- Kernel 6: mid-12-bit hist of elements in coarse bin b1 ----------
__global__ __launch_bounds__(256) void hist2_pass(const float4* __restrict__ loss4,
                                                  const Ctrl* __restrict__ ctrl,
                                                  unsigned* __restrict__ hist2,
                                                  float* __restrict__ sum2) {
  int n = blockIdx.y;
  unsigned b1 = ctrl->b1[n];
  if (b1 > 4095u) return;
  const float4* src = loss4 + (size_t)n * (HWSZ / 4);
  unsigned stride = gridDim.x * blockDim.x;
  for (unsigned i = blockIdx.x * blockDim.x + threadIdx.x; i < HWSZ / 4; i += stride) {
    float4 lv = src[i];
    const float* lp = (const float*)&lv;
#pragma unroll
    for (int j = 0; j < 4; ++j) {
      unsigned u = __float_as_uint(lp[j]);
      if ((u >> 20) == b1) {
        atomicAdd(&hist2[(size_t)n * 4096 + ((u >> 8) & 0xFFFu)], 1u);
        atomicAdd(&sum2[(size_t)n * 4096 + ((u >> 8) & 0xFFFu)], lp[j]);
      }
    }
  }
}

// ---------- Kernel 8: low-8-bit hist within 24-bit prefix ----------
__global__ __launch_bounds__(256) void hist3_pass(const float4* __restrict__ loss4,
                                                  const Ctrl* __restrict__ ctrl,
                                                  unsigned* __restrict__ hist3,
                                                  float* __restrict__ sum3) {
  int n = blockIdx.y;
  unsigned b1 = ctrl->b1[n];
  if (b1 > 4095u) return;
  unsigned pfx = (b1 << 12) | ctrl->b2[n];
  const float4* src = loss4 + (size_t)n * (HWSZ / 4);
  unsigned stride = gridDim.x * blockDim.x;
  for (unsigned i = blockIdx.x * blockDim.x + threadIdx.x; i < HWSZ / 4; i += stride) {
    float4 lv = src[i];
    const float* lp = (const float*)&lv;
#pragma unroll
    for (int j = 0; j < 4; ++j) {
      unsigned u = __float_as_uint(lp[j]);
      if ((u >> 8) == pfx) {
        atomicAdd(&hist3[(size_t)n * 256 + (u & 0xFFu)], 1u);
        atomicAdd(&sum3[(size_t)n * 256 + (u & 0xFFu)], lp[j]);
      }
    }
  }
}

// ---------- Kernel 9: final 8-bit select + per-sample loss + batch mean ----------
__global__ __launch_bounds__(512) void select_final_all(const unsigned* __restrict__ hist3,
                                                        const float* __restrict__ sum3,
                                                        Ctrl* __restrict__ ctrl,
                                                        float* __restrict__ out) {
  __shared__ float sh_loss[NB];
  int tid = threadIdx.x;
  int w = tid >> 6;        // wave index = sample
  int lane = tid & 63;
  int n = w;
  unsigned b1 = ctrl->b1[n];
  if (b1 > 4095u) {
    if (lane == 0) sh_loss[n] = ctrl->sample_loss[n];
  } else {
    const unsigned* h = hist3 + (size_t)n * 256;
    const float* fs = sum3 + (size_t)n * 256;
    unsigned rank = ctrl->rankv[n];
    int base = lane * 4;
    unsigned c = 0; float f = 0.0f;
#pragma unroll
    for (int i = 0; i < 4; ++i) { c += h[base + i]; f += fs[base + i]; }
    unsigned s = c; float g = f;
#pragma unroll
    for (int off = 1; off < 64; off <<= 1) {
      unsigned so = (unsigned)__shfl_down((int)s, off);
      float go = __shfl_down(g, off);
      if (lane + off < 64) { s += so; g += go; }
    }
    unsigned long long ball = __ballot(s >= rank);
    int chunk = 63 - (int)__clzll((unsigned long long)ball);
    if (lane == chunk) {
      unsigned cum = s - c;
      float sab = g - f;
      int bin = base;
      for (int b = base + 3; b >= base; --b) {
        unsigned cc = h[b];
        if (cum + cc >= rank) { bin = b; break; }
        cum += cc; sab += fs[b];
      }
      unsigned bits = (b1 << 20) | (ctrl->b2[n] << 8) | (unsigned)bin;
      float kth = __uint_as_float(bits);
      unsigned cg = ctrl->cnt_gt[n] + cum;
      float sg = ctrl->sum_gt[n] + sab;
      sh_loss[n] = (sg + (float)(TOPKK - (int)cg) * kth) / (float)TOPKK;
    }
  }
  __syncthreads();
  if (tid == 0) {
    float acc = 0.0f;
    for (int i = 0; i < NB; ++i) acc += sh_loss[i];
    out[0] = acc / (float)NB;
  }
}

extern "C" void kernel_launch(void* const* d_in, const int* in_sizes, int n_in,
                              void* d_out, int out_size, void* d_ws, size_t ws_size,
                              hipStream_t stream) {
  (void)in_sizes; (void)n_in; (void)out_size; (void)ws_size;
  const float* pred = (const float*)d_in[0];
  const float* weight = (const float*)d_in[1];
  const int* tgt = (const int*)d_in[2];
  char* ws = (char*)d_ws;
  unsigned* hist1 = (unsigned*)(ws + HIST1_OFF);
  float*    sum1  = (float*)(ws + SUM1_OFF);
  unsigned* hist2 = (unsigned*)(ws + HIST2_OFF);
  float*    sum2  = (float*)(ws + SUM2_OFF);
  unsigned* hist3 = (unsigned*)(ws + HIST3_OFF);
  float*    sum3  = (float*)(ws + SUM3_OFF);
  Ctrl*     ctrl  = (Ctrl*)(ws + CTRL_OFF);
  float*    pred_ds = (float*)(ws + PREDDS_OFF);
  float*    loss_full = (float*)(ws + LOSS_OFF);

  hipLaunchKernelGGL(ds_eval, dim3(96, NB), dim3(256), 0, stream,
                     pred, tgt, pred_ds, (float4*)ws);
  hipLaunchKernelGGL(select_ds, dim3(1), dim3(1024), 0, stream, pred_ds, ctrl);
  hipLaunchKernelGGL(main_pass, dim3(NB * BLOCKS_PER_SAMPLE), dim3(256), 0, stream,
                     pred, tgt, weight, ctrl, loss_full);
  hipLaunchKernelGGL(hist_pass, dim3(32, NB), dim3(256), 0, stream,
                     (const float4*)loss_full, hist1, sum1);
  hipLaunchKernelGGL(select_level, dim3(NB), dim3(64), 0, stream, hist1, sum1, ctrl, 1);
  hipLaunchKernelGGL(hist2_pass, dim3(72, NB), dim3(256), 0, stream,
                     (const float4*)loss_full, ctrl, hist2, sum2);
  hipLaunchKernelGGL(select_level, dim3(NB), dim3(64), 0, stream, hist2, sum2, ctrl, 2);
  hipLaunchKernelGGL(hist3_pass, dim3(72, NB), dim3(256), 0, stream,
                     (const float4*)loss_full, ctrl, hist3, sum3);
  hipLaunchKernelGGL(select_final_all, dim3(1), dim3(512), 0, stream,
                     hist3, sum3, ctrl, (float*)d_out);
}